// Round 8
// baseline (244.251 us; speedup 1.0000x reference)
//
#include <hip/hip_runtime.h>

#define N_ROWS 65536
#define DIM    512
#define BM     64
#define THREADS 1024

typedef unsigned short ushort_t;
typedef __bf16 bf16x8 __attribute__((ext_vector_type(8)));
typedef float  f32x4  __attribute__((ext_vector_type(4)));

union BU { uint4 u; bf16x8 b; };

__device__ __forceinline__ unsigned f2bf(float f) {
    unsigned u = __float_as_uint(f);
    return (u + 0x7fffu + ((u >> 16) & 1u)) >> 16;   // RNE f32->bf16
}

// Branchless tanh-form GELU: max abs err ~3e-3 vs exact erf GELU.
__device__ __forceinline__ float gelu_fast(float x) {
    float x2 = x * x;
    float u  = x * (0.7978845608f + 0.0356774081f * x2);
    float a  = fabsf(u);
    float t  = __expf(-2.f * a);                       // e^{-2|u|}
    float th = 1.f - 2.f * t * __builtin_amdgcn_rcpf(1.f + t);  // tanh(|u|)
    th = copysignf(th, u);
    return 0.5f * x * (1.f + th);
}

// K1a: transpose + gamma-scale (W1 only) + bf16.  W (f32 [k][n]) -> WT (bf16 [n][k])
__global__ void prep_weights(const float* __restrict__ W1,
                             const float* __restrict__ W2,
                             const float* __restrict__ gamma,
                             ushort_t* __restrict__ WT) {
    __shared__ float tile[32][33];
    const int z = blockIdx.z;
    const float* W = z ? W2 : W1;
    ushort_t* dst = WT + (size_t)z * DIM * DIM;
    int n0 = blockIdx.x * 32;
    int k0 = blockIdx.y * 32;
    for (int i = threadIdx.y; i < 32; i += 8) {
        float g = z ? 1.f : gamma[k0 + i];
        tile[i][threadIdx.x] = W[(size_t)(k0 + i) * DIM + n0 + threadIdx.x] * g;
    }
    __syncthreads();
    for (int i = threadIdx.y; i < 32; i += 8)
        dst[(size_t)(n0 + i) * DIM + k0 + threadIdx.x] =
            (ushort_t)f2bf(tile[threadIdx.x][i]);
}

// K1b: s1[c] = sum_k gamma[k]*W1[k][c];  bb1[c] = b1[c] + sum_k beta[k]*W1[k][c]
__global__ void prep_vecs(const float* __restrict__ W1,
                          const float* __restrict__ gamma,
                          const float* __restrict__ beta,
                          const float* __restrict__ b1,
                          float* __restrict__ s1, float* __restrict__ bb1) {
    const int c = blockIdx.x * 256 + threadIdx.x;
    float s = 0.f, tt = 0.f;
    #pragma unroll 8
    for (int k = 0; k < DIM; ++k) {
        float w = W1[(size_t)k * DIM + c];
        s  += gamma[k] * w;
        tt += beta[k]  * w;
    }
    s1[c]  = s;
    bb1[c] = b1[c] + tt;
}

// Fused: stage bf16(x)+stats -> GEMM1(LN-folded,+GELU) -> GEMM2(+bias,+residual)
// R6 structure (16 waves, BM=64, acc[4][2]=32 AGPR, 237->221us lineage) with:
//  - explicit 1-deep register double-buffer for B global loads in k-loops
//  - P1 loads hoisted into one batch (issue 8x float4, then process)
__global__ __launch_bounds__(THREADS, 4) void fused_mlp(
    const float* __restrict__ x, const ushort_t* __restrict__ W1T,
    const float* __restrict__ s1, const float* __restrict__ bb1,
    const ushort_t* __restrict__ W2T, const float* __restrict__ b2,
    float* __restrict__ out)
{
    __shared__ __align__(16) char smem[BM * DIM * 2];   // 64 KB, reused xb -> h1
    __shared__ float2 strow[BM];                        // {rstd, -rstd*mu} per row
    const int t    = threadIdx.x;
    const int wave = t >> 6;             // 0..15
    const int lane = t & 63;
    const int l15  = lane & 15;
    const int kb   = lane >> 4;          // 0..3
    const size_t rowbase = (size_t)blockIdx.x * BM;

    // Per-col folded-LN vectors (2 cols per wave-lane group)
    float s1v[2], bbv[2];
    #pragma unroll
    for (int n = 0; n < 2; ++n) {
        int c = wave * 32 + n * 16 + l15;
        s1v[n] = s1[c];
        bbv[n] = bb1[c];
    }

    // ---------------- Phase 1: stream x -> bf16 LDS (swizzled) + row stats ---
    {
        const int r   = t >> 4;          // 0..63
        const int sub = t & 15;          // 16 threads/row, 32 cols each
        const float4* xr = (const float4*)(x + (rowbase + r) * DIM) + sub * 8;
        const unsigned swz  = (unsigned)((r & 7) << 4);
        const unsigned base = (unsigned)(r * 1024 + sub * 64);
        float4 v[8];
        #pragma unroll
        for (int q = 0; q < 8; ++q) v[q] = xr[q];   // issue all 8 loads first
        float s = 0.f, ss = 0.f;
        #pragma unroll
        for (int q = 0; q < 8; ++q) {
            float4 a = v[q];
            s  += a.x + a.y + a.z + a.w;
            ss += a.x*a.x + a.y*a.y + a.z*a.z + a.w*a.w;
        }
        #pragma unroll
        for (int q = 0; q < 4; ++q) {
            float4 a = v[2*q], b = v[2*q+1];
            uint4 p;
            p.x = f2bf(a.x) | (f2bf(a.y) << 16);
            p.y = f2bf(a.z) | (f2bf(a.w) << 16);
            p.z = f2bf(b.x) | (f2bf(b.y) << 16);
            p.w = f2bf(b.z) | (f2bf(b.w) << 16);
            *(uint4*)(smem + ((base + (unsigned)(q * 16)) ^ swz)) = p;
        }
        #pragma unroll
        for (int m = 1; m < 16; m <<= 1) {
            s  += __shfl_xor(s,  m);
            ss += __shfl_xor(ss, m);
        }
        const float mean = s * (1.f / 512.f);
        const float var  = ss * (1.f / 512.f) - mean * mean;
        const float rstd = rsqrtf(var + 1e-5f);
        if (sub == 0) strow[r] = make_float2(rstd, -rstd * mean);
    }
    __syncthreads();

    // Common fragment addressing
    const unsigned amask = (unsigned)((l15 & 7) << 4);
    unsigned abase[4];
    #pragma unroll
    for (int m = 0; m < 4; ++m)
        abase[m] = (unsigned)((m * 16 + l15) * 1024 + kb * 16);

    const ushort_t* bw1 = W1T + (size_t)(wave * 32 + l15) * DIM + kb * 8;
    const ushort_t* bw2 = W2T + (size_t)(wave * 32 + l15) * DIM + kb * 8;

    f32x4 acc[4][2];

    // ---------------- Phase 2: GEMM1 (LN folded) + GELU -> LDS --------------
    {
        #pragma unroll
        for (int m = 0; m < 4; ++m)
            #pragma unroll
            for (int n = 0; n < 2; ++n)
                acc[m][n] = f32x4{0.f, 0.f, 0.f, 0.f};

        bf16x8 bbuf[2][2];
        #pragma unroll
        for (int n = 0; n < 2; ++n) {             // prologue: B for k0=0
            BU u; u.u = *(const uint4*)(bw1 + n * 16 * DIM);
            bbuf[0][n] = u.b;
        }
        #pragma unroll
        for (int ks = 0; ks < 16; ++ks) {
            const int cur = ks & 1, nxt = cur ^ 1;
            if (ks < 15) {                        // issue NEXT B before compute
                #pragma unroll
                for (int n = 0; n < 2; ++n) {
                    BU u; u.u = *(const uint4*)(bw1 + n * 16 * DIM + (ks + 1) * 32);
                    bbuf[nxt][n] = u.b;
                }
            }
            bf16x8 a[4];
            #pragma unroll
            for (int m = 0; m < 4; ++m) {
                BU u; u.u = *(const uint4*)(smem + ((abase[m] + (unsigned)(ks * 64)) ^ amask));
                a[m] = u.b;
            }
            #pragma unroll
            for (int m = 0; m < 4; ++m)
                #pragma unroll
                for (int n = 0; n < 2; ++n)
                    acc[m][n] = __builtin_amdgcn_mfma_f32_16x16x32_bf16(
                        a[m], bbuf[cur][n], acc[m][n], 0, 0, 0);
        }
        __syncthreads();   // all reads of xb done before overwriting with h1
        #pragma unroll
        for (int m = 0; m < 4; ++m) {
            #pragma unroll
            for (int i = 0; i < 4; ++i) {
                const int r = m * 16 + kb * 4 + i;
                const float2 sv = strow[r];     // {rstd, -rstd*mu}
                #pragma unroll
                for (int n = 0; n < 2; ++n) {
                    const int c = wave * 32 + n * 16 + l15;
                    float v = sv.x * acc[m][n][i] + sv.y * s1v[n] + bbv[n];
                    float g = gelu_fast(v);
                    *(ushort_t*)(smem + (unsigned)((r * 1024 + c * 2) ^ ((r & 7) << 4)))
                        = (ushort_t)f2bf(g);
                }
            }
        }
    }
    __syncthreads();

    // ---------------- Phase 3: GEMM2 + bias2 + residual -> out (f32) --------
    {
        #pragma unroll
        for (int m = 0; m < 4; ++m)
            #pragma unroll
            for (int n = 0; n < 2; ++n)
                acc[m][n] = f32x4{0.f, 0.f, 0.f, 0.f};

        bf16x8 bbuf[2][2];
        #pragma unroll
        for (int n = 0; n < 2; ++n) {             // prologue: B for k0=0
            BU u; u.u = *(const uint4*)(bw2 + n * 16 * DIM);
            bbuf[0][n] = u.b;
        }
        #pragma unroll
        for (int ks = 0; ks < 16; ++ks) {
            const int cur = ks & 1, nxt = cur ^ 1;
            if (ks < 15) {
                #pragma unroll
                for (int n = 0; n < 2; ++n) {
                    BU u; u.u = *(const uint4*)(bw2 + n * 16 * DIM + (ks + 1) * 32);
                    bbuf[nxt][n] = u.b;
                }
            }
            bf16x8 a[4];
            #pragma unroll
            for (int m = 0; m < 4; ++m) {
                BU u; u.u = *(const uint4*)(smem + ((abase[m] + (unsigned)(ks * 64)) ^ amask));
                a[m] = u.b;
            }
            #pragma unroll
            for (int m = 0; m < 4; ++m)
                #pragma unroll
                for (int n = 0; n < 2; ++n)
                    acc[m][n] = __builtin_amdgcn_mfma_f32_16x16x32_bf16(
                        a[m], bbuf[cur][n], acc[m][n], 0, 0, 0);
        }
        #pragma unroll
        for (int n = 0; n < 2; ++n) {
            const int c = wave * 32 + n * 16 + l15;
            const float bias = b2[c];
            #pragma unroll
            for (int m = 0; m < 4; ++m) {
                #pragma unroll
                for (int i = 0; i < 4; ++i) {
                    const int r = m * 16 + kb * 4 + i;
                    const size_t gi = (rowbase + (size_t)r) * DIM + (size_t)c;
                    out[gi] = x[gi] + (acc[m][n][i] + bias);
                }
            }
        }
    }
}

extern "C" void kernel_launch(void* const* d_in, const int* in_sizes, int n_in,
                              void* d_out, int out_size, void* d_ws, size_t ws_size,
                              hipStream_t stream) {
    const float* x     = (const float*)d_in[0];
    const float* gamma = (const float*)d_in[1];
    const float* beta  = (const float*)d_in[2];
    const float* W1    = (const float*)d_in[3];
    const float* b1    = (const float*)d_in[4];
    const float* W2    = (const float*)d_in[5];
    const float* b2    = (const float*)d_in[6];
    float* out = (float*)d_out;

    char* ws = (char*)d_ws;
    ushort_t* WT  = (ushort_t*)ws;                       // 1 MB: W1gT | W2T
    float*    s1  = (float*)(ws + 1048576);              // 2 KB
    float*    bb1 = (float*)(ws + 1048576 + 2048);       // 2 KB

    prep_weights<<<dim3(DIM / 32, DIM / 32, 2), dim3(32, 8), 0, stream>>>(W1, W2, gamma, WT);
    prep_vecs<<<dim3(2), dim3(256), 0, stream>>>(W1, gamma, beta, b1, s1, bb1);
    fused_mlp<<<dim3(N_ROWS / BM), dim3(THREADS), 0, stream>>>(
        x, WT, s1, bb1, WT + DIM * DIM, b2, out);
}

// Round 9
// 239.827 us; speedup vs baseline: 1.0184x; 1.0184x over previous
//
#include <hip/hip_runtime.h>

#define N_ROWS 65536
#define DIM    512
#define BM     64
#define THREADS 512

typedef unsigned short ushort_t;
typedef __bf16 bf16x8 __attribute__((ext_vector_type(8)));
typedef float  f32x4  __attribute__((ext_vector_type(4)));

union BU { uint4 u; bf16x8 b; };

__device__ __forceinline__ unsigned f2bf(float f) {
    unsigned u = __float_as_uint(f);
    return (u + 0x7fffu + ((u >> 16) & 1u)) >> 16;   // RNE f32->bf16
}

// Branchless tanh-form GELU: max abs err ~3e-3 vs exact erf GELU.
__device__ __forceinline__ float gelu_fast(float x) {
    float x2 = x * x;
    float u  = x * (0.7978845608f + 0.0356774081f * x2);
    float a  = fabsf(u);
    float t  = __expf(-2.f * a);                       // e^{-2|u|}
    float th = 1.f - 2.f * t * __builtin_amdgcn_rcpf(1.f + t);  // tanh(|u|)
    th = copysignf(th, u);
    return 0.5f * x * (1.f + th);
}

// K1a: transpose + gamma-scale (W1 only) + bf16.  W (f32 [k][n]) -> WT (bf16 [n][k])
__global__ void prep_weights(const float* __restrict__ W1,
                             const float* __restrict__ W2,
                             const float* __restrict__ gamma,
                             ushort_t* __restrict__ WT) {
    __shared__ float tile[32][33];
    const int z = blockIdx.z;
    const float* W = z ? W2 : W1;
    ushort_t* dst = WT + (size_t)z * DIM * DIM;
    int n0 = blockIdx.x * 32;
    int k0 = blockIdx.y * 32;
    for (int i = threadIdx.y; i < 32; i += 8) {
        float g = z ? 1.f : gamma[k0 + i];
        tile[i][threadIdx.x] = W[(size_t)(k0 + i) * DIM + n0 + threadIdx.x] * g;
    }
    __syncthreads();
    for (int i = threadIdx.y; i < 32; i += 8)
        dst[(size_t)(n0 + i) * DIM + k0 + threadIdx.x] =
            (ushort_t)f2bf(tile[threadIdx.x][i]);
}

// K1b: s1[c] = sum_k gamma[k]*W1[k][c];  bb1[c] = b1[c] + sum_k beta[k]*W1[k][c]
__global__ void prep_vecs(const float* __restrict__ W1,
                          const float* __restrict__ gamma,
                          const float* __restrict__ beta,
                          const float* __restrict__ b1,
                          float* __restrict__ s1, float* __restrict__ bb1) {
    const int c = blockIdx.x * 256 + threadIdx.x;
    float s = 0.f, tt = 0.f;
    #pragma unroll 8
    for (int k = 0; k < DIM; ++k) {
        float w = W1[(size_t)k * DIM + c];
        s  += gamma[k] * w;
        tt += beta[k]  * w;
    }
    s1[c]  = s;
    bb1[c] = b1[c] + tt;
}

// Fused: stage bf16(x)+stats -> GEMM1(LN-folded,+GELU) -> GEMM2(+bias,+residual)
// 8 waves, BM=64, per-wave 64x64 tile: acc[4][4] = 64 AGPR, arch ~55 regs.
// Total <=128 -> 4 waves/SIMD -> TWO independent blocks/CU (phase overlap),
// with no column passes and no parked pass-1 results (R7's spiller).
__global__ __launch_bounds__(THREADS, 4) void fused_mlp(
    const float* __restrict__ x, const ushort_t* __restrict__ W1T,
    const float* __restrict__ s1, const float* __restrict__ bb1,
    const ushort_t* __restrict__ W2T, const float* __restrict__ b2,
    float* __restrict__ out)
{
    __shared__ __align__(16) char smem[BM * DIM * 2];   // 64 KB, reused xb -> h1
    __shared__ float2 strow[BM];                        // {rstd, -rstd*mu} per row
    const int t    = threadIdx.x;
    const int wave = t >> 6;             // 0..7
    const int lane = t & 63;
    const int l15  = lane & 15;
    const int kb   = lane >> 4;          // 0..3
    const size_t rowbase = (size_t)blockIdx.x * BM;

    // Per-col folded-LN vectors (4 col-frags per wave)
    float s1v[4], bbv[4];
    #pragma unroll
    for (int n = 0; n < 4; ++n) {
        int c = wave * 64 + n * 16 + l15;
        s1v[n] = s1[c];
        bbv[n] = bb1[c];
    }

    // ---------------- Phase 1: stream x -> bf16 LDS (swizzled) + row stats ---
    // 8 threads/row, 64 cols each; streamed 8 floats at a time (~10 live regs).
    {
        const int r   = t >> 3;          // 0..63
        const int sub = t & 7;
        const float4* xr = (const float4*)(x + (rowbase + r) * DIM) + sub * 16;
        const unsigned swz  = (unsigned)((r & 7) << 4);
        const unsigned base = (unsigned)(r * 1024 + sub * 128);
        float s = 0.f, ss = 0.f;
        #pragma unroll
        for (int q = 0; q < 8; ++q) {
            float4 a = xr[2 * q], b = xr[2 * q + 1];
            s  += a.x + a.y + a.z + a.w + b.x + b.y + b.z + b.w;
            ss += a.x*a.x + a.y*a.y + a.z*a.z + a.w*a.w
                + b.x*b.x + b.y*b.y + b.z*b.z + b.w*b.w;
            uint4 p;
            p.x = f2bf(a.x) | (f2bf(a.y) << 16);
            p.y = f2bf(a.z) | (f2bf(a.w) << 16);
            p.z = f2bf(b.x) | (f2bf(b.y) << 16);
            p.w = f2bf(b.z) | (f2bf(b.w) << 16);
            *(uint4*)(smem + ((base + (unsigned)(q * 16)) ^ swz)) = p;
        }
        #pragma unroll
        for (int m = 1; m < 8; m <<= 1) {
            s  += __shfl_xor(s,  m);
            ss += __shfl_xor(ss, m);
        }
        const float mean = s * (1.f / 512.f);
        const float var  = ss * (1.f / 512.f) - mean * mean;
        const float rstd = rsqrtf(var + 1e-5f);
        if (sub == 0) strow[r] = make_float2(rstd, -rstd * mean);
    }
    __syncthreads();

    // Common fragment addressing
    const unsigned amask = (unsigned)((l15 & 7) << 4);
    unsigned abase[4];
    #pragma unroll
    for (int m = 0; m < 4; ++m)
        abase[m] = (unsigned)((m * 16 + l15) * 1024 + kb * 16);

    const ushort_t* bw1 = W1T + (size_t)(wave * 64 + l15) * DIM + kb * 8;
    const ushort_t* bw2 = W2T + (size_t)(wave * 64 + l15) * DIM + kb * 8;

    f32x4 acc[4][4];

    // ---------------- Phase 2: GEMM1 (LN folded) + GELU -> LDS --------------
    {
        #pragma unroll
        for (int m = 0; m < 4; ++m)
            #pragma unroll
            for (int n = 0; n < 4; ++n)
                acc[m][n] = f32x4{0.f, 0.f, 0.f, 0.f};

        #pragma unroll 2
        for (int k0 = 0; k0 < DIM; k0 += 32) {
            bf16x8 a[4], b[4];
            #pragma unroll
            for (int n = 0; n < 4; ++n) {
                BU u; u.u = *(const uint4*)(bw1 + n * 16 * DIM + k0);
                b[n] = u.b;
            }
            #pragma unroll
            for (int m = 0; m < 4; ++m) {
                BU u; u.u = *(const uint4*)(smem + ((abase[m] + (unsigned)(k0 * 2)) ^ amask));
                a[m] = u.b;
            }
            #pragma unroll
            for (int m = 0; m < 4; ++m)
                #pragma unroll
                for (int n = 0; n < 4; ++n)
                    acc[m][n] = __builtin_amdgcn_mfma_f32_16x16x32_bf16(
                        a[m], b[n], acc[m][n], 0, 0, 0);
        }
        __syncthreads();   // all reads of xb done before overwriting with h1
        #pragma unroll
        for (int m = 0; m < 4; ++m) {
            #pragma unroll
            for (int i = 0; i < 4; ++i) {
                const int r = m * 16 + kb * 4 + i;
                const float2 sv = strow[r];     // {rstd, -rstd*mu}
                #pragma unroll
                for (int n = 0; n < 4; ++n) {
                    const int c = wave * 64 + n * 16 + l15;
                    float v = sv.x * acc[m][n][i] + sv.y * s1v[n] + bbv[n];
                    float g = gelu_fast(v);
                    *(ushort_t*)(smem + (unsigned)((r * 1024 + c * 2) ^ ((r & 7) << 4)))
                        = (ushort_t)f2bf(g);
                }
            }
        }
    }
    __syncthreads();

    // ---------------- Phase 3: GEMM2 + bias2 + residual -> out (f32) --------
    {
        #pragma unroll
        for (int m = 0; m < 4; ++m)
            #pragma unroll
            for (int n = 0; n < 4; ++n)
                acc[m][n] = f32x4{0.f, 0.f, 0.f, 0.f};

        #pragma unroll 2
        for (int k0 = 0; k0 < DIM; k0 += 32) {
            bf16x8 a[4], b[4];
            #pragma unroll
            for (int n = 0; n < 4; ++n) {
                BU u; u.u = *(const uint4*)(bw2 + n * 16 * DIM + k0);
                b[n] = u.b;
            }
            #pragma unroll
            for (int m = 0; m < 4; ++m) {
                BU u; u.u = *(const uint4*)(smem + ((abase[m] + (unsigned)(k0 * 2)) ^ amask));
                a[m] = u.b;
            }
            #pragma unroll
            for (int m = 0; m < 4; ++m)
                #pragma unroll
                for (int n = 0; n < 4; ++n)
                    acc[m][n] = __builtin_amdgcn_mfma_f32_16x16x32_bf16(
                        a[m], b[n], acc[m][n], 0, 0, 0);
        }
        #pragma unroll
        for (int n = 0; n < 4; ++n) {
            const int c = wave * 64 + n * 16 + l15;
            const float bias = b2[c];
            #pragma unroll
            for (int m = 0; m < 4; ++m) {
                #pragma unroll
                for (int i = 0; i < 4; ++i) {
                    const int r = m * 16 + kb * 4 + i;
                    const size_t gi = (rowbase + (size_t)r) * DIM + (size_t)c;
                    out[gi] = x[gi] + (acc[m][n][i] + bias);
                }
            }
        }
    }
}

extern "C" void kernel_launch(void* const* d_in, const int* in_sizes, int n_in,
                              void* d_out, int out_size, void* d_ws, size_t ws_size,
                              hipStream_t stream) {
    const float* x     = (const float*)d_in[0];
    const float* gamma = (const float*)d_in[1];
    const float* beta  = (const float*)d_in[2];
    const float* W1    = (const float*)d_in[3];
    const float* b1    = (const float*)d_in[4];
    const float* W2    = (const float*)d_in[5];
    const float* b2    = (const float*)d_in[6];
    float* out = (float*)d_out;

    char* ws = (char*)d_ws;
    ushort_t* WT  = (ushort_t*)ws;                       // 1 MB: W1gT | W2T
    float*    s1  = (float*)(ws + 1048576);              // 2 KB
    float*    bb1 = (float*)(ws + 1048576 + 2048);       // 2 KB

    prep_weights<<<dim3(DIM / 32, DIM / 32, 2), dim3(32, 8), 0, stream>>>(W1, W2, gamma, WT);
    prep_vecs<<<dim3(2), dim3(256), 0, stream>>>(W1, gamma, beta, b1, s1, bb1);
    fused_mlp<<<dim3(N_ROWS / BM), dim3(THREADS), 0, stream>>>(
        x, WT, s1, bb1, WT + DIM * DIM, b2, out);
}

// Round 10
// 227.259 us; speedup vs baseline: 1.0748x; 1.0553x over previous
//
#include <hip/hip_runtime.h>

#define N_ROWS 65536
#define DIM    512
#define BM     64
#define THREADS 1024
#define XB_SZ   65536
#define BBUF_SZ 32768

typedef unsigned short ushort_t;
typedef __bf16 bf16x8 __attribute__((ext_vector_type(8)));
typedef float  f32x4  __attribute__((ext_vector_type(4)));

union BU { uint4 u; bf16x8 b; };

__device__ __forceinline__ unsigned f2bf(float f) {
    unsigned u = __float_as_uint(f);
    return (u + 0x7fffu + ((u >> 16) & 1u)) >> 16;   // RNE f32->bf16
}

// Branchless tanh-form GELU: max abs err ~3e-3 vs exact erf GELU.
__device__ __forceinline__ float gelu_fast(float x) {
    float x2 = x * x;
    float u  = x * (0.7978845608f + 0.0356774081f * x2);
    float a  = fabsf(u);
    float t  = __expf(-2.f * a);
    float th = 1.f - 2.f * t * __builtin_amdgcn_rcpf(1.f + t);
    th = copysignf(th, u);
    return 0.5f * x * (1.f + th);
}

// async global->LDS, 16 bytes per lane; lds dest = wave-uniform base + lane*16
__device__ __forceinline__ void gload_lds16(const ushort_t* g, char* l) {
    __builtin_amdgcn_global_load_lds(
        (const __attribute__((address_space(1))) unsigned int*)g,
        (__attribute__((address_space(3))) unsigned int*)l, 16, 0, 0);
}

// K1a: transpose + gamma-scale (W1 only) + bf16.  W (f32 [k][n]) -> WT (bf16 [n][k])
__global__ void prep_weights(const float* __restrict__ W1,
                             const float* __restrict__ W2,
                             const float* __restrict__ gamma,
                             ushort_t* __restrict__ WT) {
    __shared__ float tile[32][33];
    const int z = blockIdx.z;
    const float* W = z ? W2 : W1;
    ushort_t* dst = WT + (size_t)z * DIM * DIM;
    int n0 = blockIdx.x * 32;
    int k0 = blockIdx.y * 32;
    for (int i = threadIdx.y; i < 32; i += 8) {
        float g = z ? 1.f : gamma[k0 + i];
        tile[i][threadIdx.x] = W[(size_t)(k0 + i) * DIM + n0 + threadIdx.x] * g;
    }
    __syncthreads();
    for (int i = threadIdx.y; i < 32; i += 8)
        dst[(size_t)(n0 + i) * DIM + k0 + threadIdx.x] =
            (ushort_t)f2bf(tile[threadIdx.x][i]);
}

// K1b: s1[c] = sum_k gamma[k]*W1[k][c];  bb1[c] = b1[c] + sum_k beta[k]*W1[k][c]
__global__ void prep_vecs(const float* __restrict__ W1,
                          const float* __restrict__ gamma,
                          const float* __restrict__ beta,
                          const float* __restrict__ b1,
                          float* __restrict__ s1, float* __restrict__ bb1) {
    const int c = blockIdx.x * 256 + threadIdx.x;
    float s = 0.f, tt = 0.f;
    #pragma unroll 8
    for (int k = 0; k < DIM; ++k) {
        float w = W1[(size_t)k * DIM + c];
        s  += gamma[k] * w;
        tt += beta[k]  * w;
    }
    s1[c]  = s;
    bb1[c] = b1[c] + tt;
}

// Fused: stage bf16(x)+stats -> GEMM1(LN-folded,+GELU) -> GEMM2(+bias,+residual)
// R6 frame (16 waves, BM=64, acc[4][2]=32 AGPR) + B staged to LDS via
// global_load_lds double-buffer: no B regs, no L2 latency in k-loop.
__global__ __launch_bounds__(THREADS, 4) void fused_mlp(
    const float* __restrict__ x, const ushort_t* __restrict__ W1T,
    const float* __restrict__ s1, const float* __restrict__ bb1,
    const ushort_t* __restrict__ W2T, const float* __restrict__ b2,
    float* __restrict__ out)
{
    __shared__ __align__(16) char smem[XB_SZ + 2 * BBUF_SZ];  // 128 KB: xb | Bbuf0 | Bbuf1
    __shared__ float2 strow[BM];                              // {rstd, -rstd*mu}
    const int t    = threadIdx.x;
    const int wave = t >> 6;             // 0..15
    const int lane = t & 63;
    const int l15  = lane & 15;
    const int kb   = lane >> 4;          // 0..3
    const size_t rowbase = (size_t)blockIdx.x * BM;

    // ---- staging constants: wave stages 2 windows of 16 n-rows each --------
    const int nl = lane >> 2;            // 0..15 (n within window)
    const int sl = lane & 3;             // 16B slot within 64B row
    const int ssw = sl ^ ((nl >> 1) & 3);               // source-chunk permutation
    const unsigned stage_goff = (unsigned)((wave * 32 + nl) * DIM + ssw * 8); // elements
    char* const bwin0 = smem + XB_SZ + wave * 2048;     // + buf*BBUF_SZ; +1024 -> window 1

    // earliest possible: stage W1T k-step 0 into buf0 (overlaps all of P1)
    gload_lds16(W1T + stage_goff, bwin0);
    gload_lds16(W1T + stage_goff + 16 * DIM, bwin0 + 1024);

    // Per-col folded-LN vectors
    float s1v[2], bbv[2];
    #pragma unroll
    for (int n = 0; n < 2; ++n) {
        int c = wave * 32 + n * 16 + l15;
        s1v[n] = s1[c];
        bbv[n] = bb1[c];
    }

    // ---------------- Phase 1: stream x -> bf16 LDS (swizzled) + row stats ---
    {
        const int r   = t >> 4;          // 0..63
        const int sub = t & 15;          // 16 threads/row, 32 cols each
        const float4* xr = (const float4*)(x + (rowbase + r) * DIM) + sub * 8;
        const unsigned swz  = (unsigned)((r & 7) << 4);
        const unsigned base = (unsigned)(r * 1024 + sub * 64);
        float s = 0.f, ss = 0.f;
        #pragma unroll
        for (int q = 0; q < 4; ++q) {
            float4 a = xr[2 * q], b = xr[2 * q + 1];
            s  += a.x + a.y + a.z + a.w + b.x + b.y + b.z + b.w;
            ss += a.x*a.x + a.y*a.y + a.z*a.z + a.w*a.w
                + b.x*b.x + b.y*b.y + b.z*b.z + b.w*b.w;
            uint4 p;
            p.x = f2bf(a.x) | (f2bf(a.y) << 16);
            p.y = f2bf(a.z) | (f2bf(a.w) << 16);
            p.z = f2bf(b.x) | (f2bf(b.y) << 16);
            p.w = f2bf(b.z) | (f2bf(b.w) << 16);
            *(uint4*)(smem + ((base + (unsigned)(q * 16)) ^ swz)) = p;
        }
        #pragma unroll
        for (int m = 1; m < 16; m <<= 1) {
            s  += __shfl_xor(s,  m);
            ss += __shfl_xor(ss, m);
        }
        const float mean = s * (1.f / 512.f);
        const float var  = ss * (1.f / 512.f) - mean * mean;
        const float rstd = rsqrtf(var + 1e-5f);
        if (sub == 0) strow[r] = make_float2(rstd, -rstd * mean);
    }
    __syncthreads();   // xb + strow visible; buf0 staged (vmcnt drained at barrier)

    // ---- fragment addressing ----
    const unsigned amask = (unsigned)((l15 & 7) << 4);
    unsigned abase[4];
    #pragma unroll
    for (int m = 0; m < 4; ++m)
        abase[m] = (unsigned)((m * 16 + l15) * 1024 + kb * 16);
    unsigned boff[2];   // B frag read offsets within a Bbuf (swizzled slot)
    #pragma unroll
    for (int n = 0; n < 2; ++n)
        boff[n] = (unsigned)((wave * 32 + n * 16 + l15) * 64 +
                             ((kb ^ ((l15 >> 1) & 3)) * 16));

    f32x4 acc[4][2];

    // ---------------- Phase 2: GEMM1 (LN folded) + GELU -> LDS --------------
    {
        #pragma unroll
        for (int m = 0; m < 4; ++m)
            #pragma unroll
            for (int n = 0; n < 2; ++n)
                acc[m][n] = f32x4{0.f, 0.f, 0.f, 0.f};

        #pragma unroll 2
        for (int ks = 0; ks < 16; ++ks) {
            const int cur = ks & 1;
            if (ks < 15) {               // stage next k-slice into other buffer
                const ushort_t* s0 = W1T + stage_goff + (ks + 1) * 32;
                char* l0 = bwin0 + (cur ^ 1) * BBUF_SZ;
                gload_lds16(s0, l0);
                gload_lds16(s0 + 16 * DIM, l0 + 1024);
            }
            const char* bb = smem + XB_SZ + cur * BBUF_SZ;
            bf16x8 a[4], b[2];
            #pragma unroll
            for (int n = 0; n < 2; ++n) {
                BU u; u.u = *(const uint4*)(bb + boff[n]);
                b[n] = u.b;
            }
            #pragma unroll
            for (int m = 0; m < 4; ++m) {
                BU u; u.u = *(const uint4*)(smem + ((abase[m] + (unsigned)(ks * 64)) ^ amask));
                a[m] = u.b;
            }
            #pragma unroll
            for (int m = 0; m < 4; ++m)
                #pragma unroll
                for (int n = 0; n < 2; ++n)
                    acc[m][n] = __builtin_amdgcn_mfma_f32_16x16x32_bf16(
                        a[m], b[n], acc[m][n], 0, 0, 0);
            __syncthreads();             // readers done with buf[cur]; buf[cur^1] ready
        }

        // stage W2T k-step 0 into buf0 (free since ks=14's barrier) — overlaps epilogue
        gload_lds16(W2T + stage_goff, bwin0);
        gload_lds16(W2T + stage_goff + 16 * DIM, bwin0 + 1024);

        // epilogue: LN scalars + GELU -> overwrite xb with h1 (bf16, swizzled)
        #pragma unroll
        for (int m = 0; m < 4; ++m) {
            #pragma unroll
            for (int i = 0; i < 4; ++i) {
                const int r = m * 16 + kb * 4 + i;
                const float2 sv = strow[r];
                #pragma unroll
                for (int n = 0; n < 2; ++n) {
                    const int c = wave * 32 + n * 16 + l15;
                    float v = sv.x * acc[m][n][i] + sv.y * s1v[n] + bbv[n];
                    float g = gelu_fast(v);
                    *(ushort_t*)(smem + (unsigned)((r * 1024 + c * 2) ^ ((r & 7) << 4)))
                        = (ushort_t)f2bf(g);
                }
            }
        }
    }
    __syncthreads();   // h1 visible; W2T k0 staged

    // ---------------- Phase 3: GEMM2 + bias2 + residual -> out (f32) --------
    {
        #pragma unroll
        for (int m = 0; m < 4; ++m)
            #pragma unroll
            for (int n = 0; n < 2; ++n)
                acc[m][n] = f32x4{0.f, 0.f, 0.f, 0.f};

        #pragma unroll 2
        for (int ks = 0; ks < 16; ++ks) {
            const int cur = ks & 1;
            if (ks < 15) {
                const ushort_t* s0 = W2T + stage_goff + (ks + 1) * 32;
                char* l0 = bwin0 + (cur ^ 1) * BBUF_SZ;
                gload_lds16(s0, l0);
                gload_lds16(s0 + 16 * DIM, l0 + 1024);
            }
            const char* bb = smem + XB_SZ + cur * BBUF_SZ;
            bf16x8 a[4], b[2];
            #pragma unroll
            for (int n = 0; n < 2; ++n) {
                BU u; u.u = *(const uint4*)(bb + boff[n]);
                b[n] = u.b;
            }
            #pragma unroll
            for (int m = 0; m < 4; ++m) {
                BU u; u.u = *(const uint4*)(smem + ((abase[m] + (unsigned)(ks * 64)) ^ amask));
                a[m] = u.b;
            }
            #pragma unroll
            for (int m = 0; m < 4; ++m)
                #pragma unroll
                for (int n = 0; n < 2; ++n)
                    acc[m][n] = __builtin_amdgcn_mfma_f32_16x16x32_bf16(
                        a[m], b[n], acc[m][n], 0, 0, 0);
            __syncthreads();
        }
        #pragma unroll
        for (int n = 0; n < 2; ++n) {
            const int c = wave * 32 + n * 16 + l15;
            const float bias = b2[c];
            #pragma unroll
            for (int m = 0; m < 4; ++m) {
                #pragma unroll
                for (int i = 0; i < 4; ++i) {
                    const int r = m * 16 + kb * 4 + i;
                    const size_t gi = (rowbase + (size_t)r) * DIM + (size_t)c;
                    out[gi] = x[gi] + (acc[m][n][i] + bias);
                }
            }
        }
    }
}

extern "C" void kernel_launch(void* const* d_in, const int* in_sizes, int n_in,
                              void* d_out, int out_size, void* d_ws, size_t ws_size,
                              hipStream_t stream) {
    const float* x     = (const float*)d_in[0];
    const float* gamma = (const float*)d_in[1];
    const float* beta  = (const float*)d_in[2];
    const float* W1    = (const float*)d_in[3];
    const float* b1    = (const float*)d_in[4];
    const float* W2    = (const float*)d_in[5];
    const float* b2    = (const float*)d_in[6];
    float* out = (float*)d_out;

    char* ws = (char*)d_ws;
    ushort_t* WT  = (ushort_t*)ws;                       // 1 MB: W1gT | W2T
    float*    s1  = (float*)(ws + 1048576);              // 2 KB
    float*    bb1 = (float*)(ws + 1048576 + 2048);       // 2 KB

    prep_weights<<<dim3(DIM / 32, DIM / 32, 2), dim3(32, 8), 0, stream>>>(W1, W2, gamma, WT);
    prep_vecs<<<dim3(2), dim3(256), 0, stream>>>(W1, gamma, beta, b1, s1, bb1);
    fused_mlp<<<dim3(N_ROWS / BM), dim3(THREADS), 0, stream>>>(
        x, WT, s1, bb1, WT + DIM * DIM, b2, out);
}

// Round 11
// 195.636 us; speedup vs baseline: 1.2485x; 1.1616x over previous
//
#include <hip/hip_runtime.h>

#define N_ROWS 65536
#define DIM    512
#define BM     64
#define THREADS 1024
#define XB_SZ   65536
#define BBUF_SZ 32768

typedef unsigned short ushort_t;
typedef __bf16 bf16x8 __attribute__((ext_vector_type(8)));
typedef float  f32x4  __attribute__((ext_vector_type(4)));

union BU { uint4 u; bf16x8 b; };

__device__ __forceinline__ unsigned f2bf(float f) {
    unsigned u = __float_as_uint(f);
    return (u + 0x7fffu + ((u >> 16) & 1u)) >> 16;   // RNE f32->bf16
}

// Branchless tanh-form GELU: max abs err ~3e-3 vs exact erf GELU.
__device__ __forceinline__ float gelu_fast(float x) {
    float x2 = x * x;
    float u  = x * (0.7978845608f + 0.0356774081f * x2);
    float a  = fabsf(u);
    float t  = __expf(-2.f * a);
    float th = 1.f - 2.f * t * __builtin_amdgcn_rcpf(1.f + t);
    th = copysignf(th, u);
    return 0.5f * x * (1.f + th);
}

// async global->LDS, 16 bytes per lane; lds dest = wave-uniform base + lane*16
__device__ __forceinline__ void gload_lds16(const ushort_t* g, char* l) {
    __builtin_amdgcn_global_load_lds(
        (const __attribute__((address_space(1))) unsigned int*)g,
        (__attribute__((address_space(3))) unsigned int*)l, 16, 0, 0);
}

// K1a: transpose + gamma-scale (W1 only) + bf16.  W (f32 [k][n]) -> WT (bf16 [n][k])
__global__ void prep_weights(const float* __restrict__ W1,
                             const float* __restrict__ W2,
                             const float* __restrict__ gamma,
                             ushort_t* __restrict__ WT) {
    __shared__ float tile[32][33];
    const int z = blockIdx.z;
    const float* W = z ? W2 : W1;
    ushort_t* dst = WT + (size_t)z * DIM * DIM;
    int n0 = blockIdx.x * 32;
    int k0 = blockIdx.y * 32;
    for (int i = threadIdx.y; i < 32; i += 8) {
        float g = z ? 1.f : gamma[k0 + i];
        tile[i][threadIdx.x] = W[(size_t)(k0 + i) * DIM + n0 + threadIdx.x] * g;
    }
    __syncthreads();
    for (int i = threadIdx.y; i < 32; i += 8)
        dst[(size_t)(n0 + i) * DIM + k0 + threadIdx.x] =
            (ushort_t)f2bf(tile[threadIdx.x][i]);
}

// K1b: s1[c] = sum_k gamma[k]*W1[k][c];  bb1[c] = b1[c] + sum_k beta[k]*W1[k][c]
__global__ void prep_vecs(const float* __restrict__ W1,
                          const float* __restrict__ gamma,
                          const float* __restrict__ beta,
                          const float* __restrict__ b1,
                          float* __restrict__ s1, float* __restrict__ bb1) {
    const int c = blockIdx.x * 256 + threadIdx.x;
    float s = 0.f, tt = 0.f;
    #pragma unroll 8
    for (int k = 0; k < DIM; ++k) {
        float w = W1[(size_t)k * DIM + c];
        s  += gamma[k] * w;
        tt += beta[k]  * w;
    }
    s1[c]  = s;
    bb1[c] = b1[c] + tt;
}

// Fused: stage bf16(x)+stats -> GEMM1(LN-folded,+GELU) -> GEMM2(+bias,+residual)
// R10 frame + BARRIER-FREE k-loops: B double-buffers are wave-private
// (each wave stages and reads only its own 2KB windows), so per-step
// __syncthreads is replaced by per-wave counted s_waitcnt vmcnt(2).
__global__ __launch_bounds__(THREADS, 4) void fused_mlp(
    const float* __restrict__ x, const ushort_t* __restrict__ W1T,
    const float* __restrict__ s1, const float* __restrict__ bb1,
    const ushort_t* __restrict__ W2T, const float* __restrict__ b2,
    float* __restrict__ out)
{
    __shared__ __align__(16) char smem[XB_SZ + 2 * BBUF_SZ];  // 128 KB: xb | Bbuf0 | Bbuf1
    __shared__ float2 strow[BM];                              // {rstd, -rstd*mu}
    const int t    = threadIdx.x;
    const int wave = t >> 6;             // 0..15
    const int lane = t & 63;
    const int l15  = lane & 15;
    const int kb   = lane >> 4;          // 0..3
    const size_t rowbase = (size_t)blockIdx.x * BM;

    // ---- staging constants: wave stages 2 windows of 16 n-rows each --------
    const int nl = lane >> 2;            // 0..15 (n within window)
    const int sl = lane & 3;             // 16B slot within 64B row
    const int ssw = sl ^ ((nl >> 1) & 3);               // source-chunk permutation
    const unsigned stage_goff = (unsigned)((wave * 32 + nl) * DIM + ssw * 8); // elements
    char* const bwin0 = smem + XB_SZ + wave * 2048;     // + buf*BBUF_SZ; +1024 -> window 1

    // earliest possible: stage W1T k-step 0 into buf0 (overlaps all of P1)
    gload_lds16(W1T + stage_goff, bwin0);
    gload_lds16(W1T + stage_goff + 16 * DIM, bwin0 + 1024);

    // Per-col folded-LN vectors
    float s1v[2], bbv[2];
    #pragma unroll
    for (int n = 0; n < 2; ++n) {
        int c = wave * 32 + n * 16 + l15;
        s1v[n] = s1[c];
        bbv[n] = bb1[c];
    }

    // ---------------- Phase 1: stream x -> bf16 LDS (swizzled) + row stats ---
    {
        const int r   = t >> 4;          // 0..63
        const int sub = t & 15;          // 16 threads/row, 32 cols each
        const float4* xr = (const float4*)(x + (rowbase + r) * DIM) + sub * 8;
        const unsigned swz  = (unsigned)((r & 7) << 4);
        const unsigned base = (unsigned)(r * 1024 + sub * 64);
        float s = 0.f, ss = 0.f;
        #pragma unroll
        for (int q = 0; q < 4; ++q) {
            float4 a = xr[2 * q], b = xr[2 * q + 1];
            s  += a.x + a.y + a.z + a.w + b.x + b.y + b.z + b.w;
            ss += a.x*a.x + a.y*a.y + a.z*a.z + a.w*a.w
                + b.x*b.x + b.y*b.y + b.z*b.z + b.w*b.w;
            uint4 p;
            p.x = f2bf(a.x) | (f2bf(a.y) << 16);
            p.y = f2bf(a.z) | (f2bf(a.w) << 16);
            p.z = f2bf(b.x) | (f2bf(b.y) << 16);
            p.w = f2bf(b.z) | (f2bf(b.w) << 16);
            *(uint4*)(smem + ((base + (unsigned)(q * 16)) ^ swz)) = p;
        }
        #pragma unroll
        for (int m = 1; m < 16; m <<= 1) {
            s  += __shfl_xor(s,  m);
            ss += __shfl_xor(ss, m);
        }
        const float mean = s * (1.f / 512.f);
        const float var  = ss * (1.f / 512.f) - mean * mean;
        const float rstd = rsqrtf(var + 1e-5f);
        if (sub == 0) strow[r] = make_float2(rstd, -rstd * mean);
    }
    __syncthreads();   // xb + strow visible; buf0 DMA drained by barrier

    // ---- fragment addressing ----
    const unsigned amask = (unsigned)((l15 & 7) << 4);
    unsigned abase[4];
    #pragma unroll
    for (int m = 0; m < 4; ++m)
        abase[m] = (unsigned)((m * 16 + l15) * 1024 + kb * 16);
    unsigned boff[2];   // B frag read offsets within a Bbuf (swizzled slot)
    #pragma unroll
    for (int n = 0; n < 2; ++n)
        boff[n] = (unsigned)((wave * 32 + n * 16 + l15) * 64 +
                             ((kb ^ ((l15 >> 1) & 3)) * 16));

    f32x4 acc[4][2];

    // ---------------- Phase 2: GEMM1 (LN folded) + GELU -> LDS --------------
    {
        #pragma unroll
        for (int m = 0; m < 4; ++m)
            #pragma unroll
            for (int n = 0; n < 2; ++n)
                acc[m][n] = f32x4{0.f, 0.f, 0.f, 0.f};

        #pragma unroll 2
        for (int ks = 0; ks < 16; ++ks) {
            const int cur = ks & 1;
            // prev step's ds_reads complete (near-free; MFMAs forced most) so
            // the DMA below can't overwrite a buffer still being sampled.
            asm volatile("s_waitcnt lgkmcnt(0)" ::: "memory");
            if (ks < 15) {               // stage next k-slice into other buffer
                const ushort_t* s0 = W1T + stage_goff + (ks + 1) * 32;
                char* l0 = bwin0 + (cur ^ 1) * BBUF_SZ;
                gload_lds16(s0, l0);
                gload_lds16(s0 + 16 * DIM, l0 + 1024);
                asm volatile("s_waitcnt vmcnt(2)" ::: "memory");  // slice ks landed
            } else {
                asm volatile("s_waitcnt vmcnt(0)" ::: "memory");
            }
            __builtin_amdgcn_sched_barrier(0);
            const char* bb = smem + XB_SZ + cur * BBUF_SZ;
            bf16x8 a[4], b[2];
            #pragma unroll
            for (int n = 0; n < 2; ++n) {
                BU u; u.u = *(const uint4*)(bb + boff[n]);
                b[n] = u.b;
            }
            #pragma unroll
            for (int m = 0; m < 4; ++m) {
                BU u; u.u = *(const uint4*)(smem + ((abase[m] + (unsigned)(ks * 64)) ^ amask));
                a[m] = u.b;
            }
            #pragma unroll
            for (int m = 0; m < 4; ++m)
                #pragma unroll
                for (int n = 0; n < 2; ++n)
                    acc[m][n] = __builtin_amdgcn_mfma_f32_16x16x32_bf16(
                        a[m], b[n], acc[m][n], 0, 0, 0);
        }
        __syncthreads();   // all waves done reading xb

        // stage W2T k-step 0 into buf0 — overlaps GELU epilogue
        gload_lds16(W2T + stage_goff, bwin0);
        gload_lds16(W2T + stage_goff + 16 * DIM, bwin0 + 1024);

        // epilogue: LN scalars + GELU -> overwrite xb with h1 (bf16, swizzled)
        #pragma unroll
        for (int m = 0; m < 4; ++m) {
            #pragma unroll
            for (int i = 0; i < 4; ++i) {
                const int r = m * 16 + kb * 4 + i;
                const float2 sv = strow[r];
                #pragma unroll
                for (int n = 0; n < 2; ++n) {
                    const int c = wave * 32 + n * 16 + l15;
                    float v = sv.x * acc[m][n][i] + sv.y * s1v[n] + bbv[n];
                    float g = gelu_fast(v);
                    *(ushort_t*)(smem + (unsigned)((r * 1024 + c * 2) ^ ((r & 7) << 4)))
                        = (ushort_t)f2bf(g);
                }
            }
        }
    }
    __syncthreads();   // h1 visible; W2T slice0 DMA drained by barrier

    // ---------------- Phase 3: GEMM2 + bias2 + residual -> out (f32) --------
    {
        #pragma unroll
        for (int m = 0; m < 4; ++m)
            #pragma unroll
            for (int n = 0; n < 2; ++n)
                acc[m][n] = f32x4{0.f, 0.f, 0.f, 0.f};

        #pragma unroll 2
        for (int ks = 0; ks < 16; ++ks) {
            const int cur = ks & 1;
            asm volatile("s_waitcnt lgkmcnt(0)" ::: "memory");
            if (ks < 15) {
                const ushort_t* s0 = W2T + stage_goff + (ks + 1) * 32;
                char* l0 = bwin0 + (cur ^ 1) * BBUF_SZ;
                gload_lds16(s0, l0);
                gload_lds16(s0 + 16 * DIM, l0 + 1024);
                asm volatile("s_waitcnt vmcnt(2)" ::: "memory");
            } else {
                asm volatile("s_waitcnt vmcnt(0)" ::: "memory");
            }
            __builtin_amdgcn_sched_barrier(0);
            const char* bb = smem + XB_SZ + cur * BBUF_SZ;
            bf16x8 a[4], b[2];
            #pragma unroll
            for (int n = 0; n < 2; ++n) {
                BU u; u.u = *(const uint4*)(bb + boff[n]);
                b[n] = u.b;
            }
            #pragma unroll
            for (int m = 0; m < 4; ++m) {
                BU u; u.u = *(const uint4*)(smem + ((abase[m] + (unsigned)(ks * 64)) ^ amask));
                a[m] = u.b;
            }
            #pragma unroll
            for (int m = 0; m < 4; ++m)
                #pragma unroll
                for (int n = 0; n < 2; ++n)
                    acc[m][n] = __builtin_amdgcn_mfma_f32_16x16x32_bf16(
                        a[m], b[n], acc[m][n], 0, 0, 0);
        }
        #pragma unroll
        for (int n = 0; n < 2; ++n) {
            const int c = wave * 32 + n * 16 + l15;
            const float bias = b2[c];
            #pragma unroll
            for (int m = 0; m < 4; ++m) {
                #pragma unroll
                for (int i = 0; i < 4; ++i) {
                    const int r = m * 16 + kb * 4 + i;
                    const size_t gi = (rowbase + (size_t)r) * DIM + (size_t)c;
                    out[gi] = x[gi] + (acc[m][n][i] + bias);
                }
            }
        }
    }
}

extern "C" void kernel_launch(void* const* d_in, const int* in_sizes, int n_in,
                              void* d_out, int out_size, void* d_ws, size_t ws_size,
                              hipStream_t stream) {
    const float* x     = (const float*)d_in[0];
    const float* gamma = (const float*)d_in[1];
    const float* beta  = (const float*)d_in[2];
    const float* W1    = (const float*)d_in[3];
    const float* b1    = (const float*)d_in[4];
    const float* W2    = (const float*)d_in[5];
    const float* b2    = (const float*)d_in[6];
    float* out = (float*)d_out;

    char* ws = (char*)d_ws;
    ushort_t* WT  = (ushort_t*)ws;                       // 1 MB: W1gT | W2T
    float*    s1  = (float*)(ws + 1048576);              // 2 KB
    float*    bb1 = (float*)(ws + 1048576 + 2048);       // 2 KB

    prep_weights<<<dim3(DIM / 32, DIM / 32, 2), dim3(32, 8), 0, stream>>>(W1, W2, gamma, WT);
    prep_vecs<<<dim3(2), dim3(256), 0, stream>>>(W1, gamma, beta, b1, s1, bb1);
    fused_mlp<<<dim3(N_ROWS / BM), dim3(THREADS), 0, stream>>>(
        x, WT, s1, bb1, WT + DIM * DIM, b2, out);
}